// Round 5
// baseline (214.266 us; speedup 1.0000x reference)
//
#include <hip/hip_runtime.h>

// TopNGating: B=2, N=4096, DIM=2048, 8 experts, top-2, cap=640
// Outputs (concat): dispatch[2,4096,8,640], combine[2,4096,8,640], balance_loss, router_z_loss

#define DIMX 2048
#define NG   8
#define NB   2
#define NSEQ 4096
#define NTOK (NB*NSEQ)
#define CAPE 640
#define ROW  (NG*CAPE)                 // 5120 floats per token per tensor
#define DCNT ((size_t)NTOK*ROW)        // 41943040 floats per dense output

struct Ws {
  int   pk[NTOK];                 // e0 | e1<<4 | routed1<<8
  float g0[NTOK];                 // renormalized top-1 gate
  float g1[NTOK];                 // renormalized top-2 gate
  float z2[NTOK];                 // lse^2 per token
  int   pos0[NTOK];               // capacity slot or -1
  int   pos1[NTOK];
  float raws_t[NG][NTOK];         // raw softmax gates, transposed [e][token]
};

// ---------------- gate logits + softmax + top2 + routing decisions ----------------
// 512 blocks x 512 threads (8 waves); each wave gates 4 tokens, amortizing the
// W LDS reads 4x (16 ds_read_b128/token instead of 64). Math per token is
// bit-identical to the R2 kernel (same FMA order, same 32..1 butterfly).
__global__ __launch_bounds__(512, 4) void kgate(const float* __restrict__ x,
                                                const float* __restrict__ W,
                                                const float* __restrict__ probs,
                                                Ws* __restrict__ ws) {
  __shared__ float4 Wl[NG * 512];
  int tid = threadIdx.x;
  for (int i = tid; i < NG * 512; i += 512) Wl[i] = ((const float4*)W)[i];
  __syncthreads();

  int wave = tid >> 6, lane = tid & 63;
  int t0 = blockIdx.x * 32 + wave * 4;          // grid = NTOK/32 = 512 blocks

  const float4* xp0 = (const float4*)(x + (size_t)(t0 + 0) * DIMX);
  const float4* xp1 = (const float4*)(x + (size_t)(t0 + 1) * DIMX);
  const float4* xp2 = (const float4*)(x + (size_t)(t0 + 2) * DIMX);
  const float4* xp3 = (const float4*)(x + (size_t)(t0 + 3) * DIMX);

  float acc[4][NG];
#pragma unroll
  for (int tk = 0; tk < 4; ++tk)
#pragma unroll
    for (int e = 0; e < NG; ++e) acc[tk][e] = 0.f;

#pragma unroll
  for (int j = 0; j < 8; ++j) {
    float4 x0 = xp0[j * 64 + lane];
    float4 x1 = xp1[j * 64 + lane];
    float4 x2 = xp2[j * 64 + lane];
    float4 x3 = xp3[j * 64 + lane];
#pragma unroll
    for (int e = 0; e < NG; ++e) {
      float4 w = Wl[e * 512 + j * 64 + lane];
      acc[0][e] = fmaf(x0.x, w.x, acc[0][e]);
      acc[0][e] = fmaf(x0.y, w.y, acc[0][e]);
      acc[0][e] = fmaf(x0.z, w.z, acc[0][e]);
      acc[0][e] = fmaf(x0.w, w.w, acc[0][e]);
      acc[1][e] = fmaf(x1.x, w.x, acc[1][e]);
      acc[1][e] = fmaf(x1.y, w.y, acc[1][e]);
      acc[1][e] = fmaf(x1.z, w.z, acc[1][e]);
      acc[1][e] = fmaf(x1.w, w.w, acc[1][e]);
      acc[2][e] = fmaf(x2.x, w.x, acc[2][e]);
      acc[2][e] = fmaf(x2.y, w.y, acc[2][e]);
      acc[2][e] = fmaf(x2.z, w.z, acc[2][e]);
      acc[2][e] = fmaf(x2.w, w.w, acc[2][e]);
      acc[3][e] = fmaf(x3.x, w.x, acc[3][e]);
      acc[3][e] = fmaf(x3.y, w.y, acc[3][e]);
      acc[3][e] = fmaf(x3.z, w.z, acc[3][e]);
      acc[3][e] = fmaf(x3.w, w.w, acc[3][e]);
    }
  }

#pragma unroll
  for (int tk = 0; tk < 4; ++tk) {
    int token = t0 + tk;
    float a[NG];
#pragma unroll
    for (int e = 0; e < NG; ++e) a[e] = acc[tk][e];
#pragma unroll
    for (int e = 0; e < NG; ++e) {
#pragma unroll
      for (int off = 32; off > 0; off >>= 1) a[e] += __shfl_xor(a[e], off, 64);
    }

    // softmax over 8 gates (wave-uniform, redundant on all lanes)
    float m = a[0];
#pragma unroll
    for (int e = 1; e < NG; ++e) m = fmaxf(m, a[e]);
    float ex[NG], s = 0.f;
#pragma unroll
    for (int e = 0; e < NG; ++e) { ex[e] = expf(a[e] - m); s += ex[e]; }
    float raw[NG];
#pragma unroll
    for (int e = 0; e < NG; ++e) raw[e] = ex[e] / s;

    // top-2, ties -> lowest index (strict >)
    int e0i = 0; float g0v = raw[0];
#pragma unroll
    for (int e = 1; e < NG; ++e) if (raw[e] > g0v) { g0v = raw[e]; e0i = e; }
    int e1i = -1; float g1v = -1.f;
#pragma unroll
    for (int e = 0; e < NG; ++e) if (e != e0i && raw[e] > g1v) { g1v = raw[e]; e1i = e; }

    float denom = g0v + g1v;
    if (denom < 1e-9f) denom = 1e-9f;
    float g0n = g0v / denom, g1n = g1v / denom;

    float p1 = probs[NTOK + token];               // probs[1][b][n], b*NSEQ+n == token
    int r = (p1 < (g1n / 0.2f)) ? 1 : 0;          // threshold_train = 0.2

    float lse = m + logf(s);

    if (lane < NG) ws->raws_t[lane][token] = raw[lane];
    if (lane == 0) {
      ws->pk[token] = e0i | (e1i << 4) | (r << 8);
      ws->g0[token] = g0n;  ws->g1[token] = g1n;
      ws->z2[token] = lse * lse;
    }
  }
}

// ---------------- per-(b,e) exclusive prefix scans with capacity + fused losses ----------------
__global__ __launch_bounds__(256) void kscan(Ws* __restrict__ ws, float* __restrict__ losses) {
  __shared__ int   wtot[4];
  __shared__ float wsum[4];
  __shared__ float zsum[4];
  int be = blockIdx.x, b = be >> 3, e = be & 7;
  int t = threadIdx.x, wave = t >> 6, lane = t & 63;
  int base = b * NSEQ;

  // each thread owns 16 consecutive tokens; wave covers contiguous 4KB -> coalesced int4
  int pk[16];
  {
    const int4* pp = (const int4*)(ws->pk + base + t * 16);
#pragma unroll
    for (int j = 0; j < 4; ++j) {
      int4 v = pp[j];
      pk[4*j] = v.x; pk[4*j+1] = v.y; pk[4*j+2] = v.z; pk[4*j+3] = v.w;
    }
  }

  // density_1_proxy partial: sum raw gates for this (b,e)  (transposed -> contiguous)
  float ps = 0.f;
  {
    const float* rp = ws->raws_t[e] + base + t * 16;
#pragma unroll
    for (int i = 0; i < 16; ++i) ps += rp[i];
  }
#pragma unroll
  for (int off = 32; off > 0; off >>= 1) ps += __shfl_xor(ps, off, 64);
  if (lane == 0) wsum[wave] = ps;

  // z-loss slice: this block reduces z2[be*512 .. be*512+512) = 128 float4s
  float zs = 0.f;
  if (t < 128) {
    float4 v = ((const float4*)ws->z2)[be * 128 + t];
    zs = v.x + v.y + v.z + v.w;
  }
#pragma unroll
  for (int off = 32; off > 0; off >>= 1) zs += __shfl_xor(zs, off, 64);
  if (lane == 0) zsum[wave] = zs;

  // ---- k = 0 (always routed) ----
  int cnt = 0;
#pragma unroll
  for (int i = 0; i < 16; ++i) cnt += ((pk[i] & 15) == e);
  int incl = cnt;
#pragma unroll
  for (int off = 1; off < 64; off <<= 1) { int v = __shfl_up(incl, off, 64); if (lane >= off) incl += v; }
  if (lane == 63) wtot[wave] = incl;
  __syncthreads();
  int woff = 0, tot = 0;
#pragma unroll
  for (int w = 0; w < 4; ++w) { int v = wtot[w]; tot += v; if (w < wave) woff += v; }
  int c0 = min(tot, CAPE);
  int p = woff + incl - cnt;          // exclusive prefix for this thread's first token
#pragma unroll
  for (int i = 0; i < 16; ++i) {
    if ((pk[i] & 15) == e) { ws->pos0[base + t * 16 + i] = (p < CAPE) ? p : -1; ++p; }
  }
  __syncthreads();   // wtot reuse

  // ---- k = 1 (offset by capacity-clipped top-1 count) ----
  cnt = 0;
#pragma unroll
  for (int i = 0; i < 16; ++i) cnt += ((((pk[i] >> 4) & 15) == e) && (pk[i] & 0x100));
  incl = cnt;
#pragma unroll
  for (int off = 1; off < 64; off <<= 1) { int v = __shfl_up(incl, off, 64); if (lane >= off) incl += v; }
  if (lane == 63) wtot[wave] = incl;
  __syncthreads();
  woff = 0;
#pragma unroll
  for (int w = 0; w < 4; ++w) { int v = wtot[w]; if (w < wave) woff += v; }
  p = woff + incl - cnt;
#pragma unroll
  for (int i = 0; i < 16; ++i) {
    if ((((pk[i] >> 4) & 15) == e)) {
      if (pk[i] & 0x100) { int q = p + c0; ws->pos1[base + t * 16 + i] = (q < CAPE) ? q : -1; ++p; }
      else               { ws->pos1[base + t * 16 + i] = -1; }
    }
  }

  if (t == 0) {
    float psum = wsum[0] + wsum[1] + wsum[2] + wsum[3];
    float ztot = zsum[0] + zsum[1] + zsum[2] + zsum[3];
    // balance term: (proxy/NSEQ) * (c0/NSEQ) summed over 16 (b,e), /16 * 64
    atomicAdd(losses + 0, psum * (1.f / NSEQ) * ((float)c0 * (1.f / NSEQ)) * 4.f);
    atomicAdd(losses + 1, ztot * (1.f / NTOK));
  }
}

// ---------------- fused zero-fill + scatter ----------------
// one 256-thread block per token: writes that token's 5120-float row of
// dispatch AND combine in a single streaming pass, nonzeros inserted inline.
__global__ __launch_bounds__(256) void kout(const Ws* __restrict__ ws, float* __restrict__ out) {
  int token = blockIdx.x;
  int t = threadIdx.x;
  int pkv = ws->pk[token];
  int e0 = pkv & 15, e1 = (pkv >> 4) & 15;
  int p0 = ws->pos0[token], p1 = ws->pos1[token];
  float g0 = ws->g0[token], g1 = ws->g1[token];
  int o0 = (p0 >= 0) ? e0 * CAPE + p0 : -16;    // -16: never matches any rel in [0,4)
  int o1 = (p1 >= 0) ? e1 * CAPE + p1 : -16;

  float* drow = out + (size_t)token * ROW;
  float* crow = out + DCNT + (size_t)token * ROW;

#pragma unroll
  for (int c = 0; c < 5; ++c) {
    int off = c * 1024 + t * 4;
    int r0 = o0 - off, r1 = o1 - off;
    float4 dv, cv;
    dv.x = ((r0 == 0) | (r1 == 0)) ? 1.f : 0.f;
    dv.y = ((r0 == 1) | (r1 == 1)) ? 1.f : 0.f;
    dv.z = ((r0 == 2) | (r1 == 2)) ? 1.f : 0.f;
    dv.w = ((r0 == 3) | (r1 == 3)) ? 1.f : 0.f;
    cv.x = (r0 == 0) ? g0 : ((r1 == 0) ? g1 : 0.f);
    cv.y = (r0 == 1) ? g0 : ((r1 == 1) ? g1 : 0.f);
    cv.z = (r0 == 2) ? g0 : ((r1 == 2) ? g1 : 0.f);
    cv.w = (r0 == 3) ? g0 : ((r1 == 3) ? g1 : 0.f);
    *(float4*)(drow + off) = dv;
    *(float4*)(crow + off) = cv;
  }
}

extern "C" void kernel_launch(void* const* d_in, const int* in_sizes, int n_in,
                              void* d_out, int out_size, void* d_ws, size_t ws_size,
                              hipStream_t stream) {
  const float* x     = (const float*)d_in[0];
  const float* W     = (const float*)d_in[1];
  const float* probs = (const float*)d_in[2];
  float* out = (float*)d_out;
  Ws* ws = (Ws*)d_ws;

  hipMemsetAsync(out + 2 * DCNT, 0, 2 * sizeof(float), stream);   // loss accumulators
  kgate<<<NTOK / 32, 512, 0, stream>>>(x, W, probs, ws);
  kscan<<<16, 256, 0, stream>>>(ws, out + 2 * DCNT);
  kout<<<NTOK, 256, 0, stream>>>(ws, out);
}

// Round 6
// 198.827 us; speedup vs baseline: 1.0776x; 1.0776x over previous
//
#include <hip/hip_runtime.h>

// TopNGating: B=2, N=4096, DIM=2048, 8 experts, top-2, cap=640
// Outputs (concat): dispatch[2,4096,8,640], combine[2,4096,8,640], balance_loss, router_z_loss

#define DIMX 2048
#define NG   8
#define NB   2
#define NSEQ 4096
#define NTOK (NB*NSEQ)
#define CAPE 640
#define ROW  (NG*CAPE)                 // 5120 floats per token per tensor
#define DCNT ((size_t)NTOK*ROW)        // 41943040 floats per dense output

struct Ws {
  int   pk[NTOK];                 // e0 | e1<<4 | routed1<<8
  float g0[NTOK];                 // renormalized top-1 gate
  float g1[NTOK];                 // renormalized top-2 gate
  float z2[NTOK];                 // lse^2 per token
  int   pos0[NTOK];               // capacity slot or -1
  int   pos1[NTOK];
  float raws_t[NG][NTOK];         // raw softmax gates, transposed [e][token]
  float proxy[16];                // per (b,e) sum of raw gates over n
  float zpart[16];                // per-block partial of sum(z2)
  int   cnt0[16];                 // per (b,e) capacity-clipped top-1 count
};

// ---------------- gate logits + softmax + top2 + routing decisions ----------------
// 512 blocks x 512 threads (8 waves); each wave gates 4 tokens, amortizing the
// W LDS reads 4x (16 ds_read_b128/token instead of 64).
__global__ __launch_bounds__(512, 4) void kgate(const float* __restrict__ x,
                                                const float* __restrict__ W,
                                                const float* __restrict__ probs,
                                                Ws* __restrict__ ws) {
  __shared__ float4 Wl[NG * 512];
  int tid = threadIdx.x;
  for (int i = tid; i < NG * 512; i += 512) Wl[i] = ((const float4*)W)[i];
  __syncthreads();

  int wave = tid >> 6, lane = tid & 63;
  int t0 = blockIdx.x * 32 + wave * 4;          // grid = NTOK/32 = 512 blocks

  const float4* xp0 = (const float4*)(x + (size_t)(t0 + 0) * DIMX);
  const float4* xp1 = (const float4*)(x + (size_t)(t0 + 1) * DIMX);
  const float4* xp2 = (const float4*)(x + (size_t)(t0 + 2) * DIMX);
  const float4* xp3 = (const float4*)(x + (size_t)(t0 + 3) * DIMX);

  float acc[4][NG];
#pragma unroll
  for (int tk = 0; tk < 4; ++tk)
#pragma unroll
    for (int e = 0; e < NG; ++e) acc[tk][e] = 0.f;

#pragma unroll
  for (int j = 0; j < 8; ++j) {
    float4 x0 = xp0[j * 64 + lane];
    float4 x1 = xp1[j * 64 + lane];
    float4 x2 = xp2[j * 64 + lane];
    float4 x3 = xp3[j * 64 + lane];
#pragma unroll
    for (int e = 0; e < NG; ++e) {
      float4 w = Wl[e * 512 + j * 64 + lane];
      acc[0][e] = fmaf(x0.x, w.x, acc[0][e]);
      acc[0][e] = fmaf(x0.y, w.y, acc[0][e]);
      acc[0][e] = fmaf(x0.z, w.z, acc[0][e]);
      acc[0][e] = fmaf(x0.w, w.w, acc[0][e]);
      acc[1][e] = fmaf(x1.x, w.x, acc[1][e]);
      acc[1][e] = fmaf(x1.y, w.y, acc[1][e]);
      acc[1][e] = fmaf(x1.z, w.z, acc[1][e]);
      acc[1][e] = fmaf(x1.w, w.w, acc[1][e]);
      acc[2][e] = fmaf(x2.x, w.x, acc[2][e]);
      acc[2][e] = fmaf(x2.y, w.y, acc[2][e]);
      acc[2][e] = fmaf(x2.z, w.z, acc[2][e]);
      acc[2][e] = fmaf(x2.w, w.w, acc[2][e]);
      acc[3][e] = fmaf(x3.x, w.x, acc[3][e]);
      acc[3][e] = fmaf(x3.y, w.y, acc[3][e]);
      acc[3][e] = fmaf(x3.z, w.z, acc[3][e]);
      acc[3][e] = fmaf(x3.w, w.w, acc[3][e]);
    }
  }

#pragma unroll
  for (int tk = 0; tk < 4; ++tk) {
    int token = t0 + tk;
    float a[NG];
#pragma unroll
    for (int e = 0; e < NG; ++e) a[e] = acc[tk][e];
#pragma unroll
    for (int e = 0; e < NG; ++e) {
#pragma unroll
      for (int off = 32; off > 0; off >>= 1) a[e] += __shfl_xor(a[e], off, 64);
    }

    // softmax over 8 gates (wave-uniform, redundant on all lanes)
    float m = a[0];
#pragma unroll
    for (int e = 1; e < NG; ++e) m = fmaxf(m, a[e]);
    float ex[NG], s = 0.f;
#pragma unroll
    for (int e = 0; e < NG; ++e) { ex[e] = expf(a[e] - m); s += ex[e]; }
    float raw[NG];
#pragma unroll
    for (int e = 0; e < NG; ++e) raw[e] = ex[e] / s;

    // top-2, ties -> lowest index (strict >)
    int e0i = 0; float g0v = raw[0];
#pragma unroll
    for (int e = 1; e < NG; ++e) if (raw[e] > g0v) { g0v = raw[e]; e0i = e; }
    int e1i = -1; float g1v = -1.f;
#pragma unroll
    for (int e = 0; e < NG; ++e) if (e != e0i && raw[e] > g1v) { g1v = raw[e]; e1i = e; }

    float denom = g0v + g1v;
    if (denom < 1e-9f) denom = 1e-9f;
    float g0n = g0v / denom, g1n = g1v / denom;

    float p1 = probs[NTOK + token];               // probs[1][b][n], b*NSEQ+n == token
    int r = (p1 < (g1n / 0.2f)) ? 1 : 0;          // threshold_train = 0.2

    float lse = m + logf(s);

    if (lane < NG) ws->raws_t[lane][token] = raw[lane];
    if (lane == 0) {
      ws->pk[token] = e0i | (e1i << 4) | (r << 8);
      ws->g0[token] = g0n;  ws->g1[token] = g1n;
      ws->z2[token] = lse * lse;
    }
  }
}

// ---------------- per-(b,e) exclusive prefix scans with capacity + loss partials ----------------
__global__ __launch_bounds__(256) void kscan(Ws* __restrict__ ws) {
  __shared__ int   wtot[4];
  __shared__ float wsum[4];
  __shared__ float zsum[4];
  int be = blockIdx.x, b = be >> 3, e = be & 7;
  int t = threadIdx.x, wave = t >> 6, lane = t & 63;
  int base = b * NSEQ;

  // each thread owns 16 consecutive tokens; wave covers contiguous 4KB -> coalesced int4
  int pk[16];
  {
    const int4* pp = (const int4*)(ws->pk + base + t * 16);
#pragma unroll
    for (int j = 0; j < 4; ++j) {
      int4 v = pp[j];
      pk[4*j] = v.x; pk[4*j+1] = v.y; pk[4*j+2] = v.z; pk[4*j+3] = v.w;
    }
  }

  // density_1_proxy partial: sum raw gates for this (b,e)  (transposed -> contiguous)
  float ps = 0.f;
  {
    const float* rp = ws->raws_t[e] + base + t * 16;
#pragma unroll
    for (int i = 0; i < 16; ++i) ps += rp[i];
  }
#pragma unroll
  for (int off = 32; off > 0; off >>= 1) ps += __shfl_xor(ps, off, 64);
  if (lane == 0) wsum[wave] = ps;

  // z-loss slice: this block reduces z2[be*512 .. be*512+512) = 128 float4s
  float zs = 0.f;
  if (t < 128) {
    float4 v = ((const float4*)ws->z2)[be * 128 + t];
    zs = v.x + v.y + v.z + v.w;
  }
#pragma unroll
  for (int off = 32; off > 0; off >>= 1) zs += __shfl_xor(zs, off, 64);
  if (lane == 0) zsum[wave] = zs;

  // ---- k = 0 (always routed) ----
  int cnt = 0;
#pragma unroll
  for (int i = 0; i < 16; ++i) cnt += ((pk[i] & 15) == e);
  int incl = cnt;
#pragma unroll
  for (int off = 1; off < 64; off <<= 1) { int v = __shfl_up(incl, off, 64); if (lane >= off) incl += v; }
  if (lane == 63) wtot[wave] = incl;
  __syncthreads();
  int woff = 0, tot = 0;
#pragma unroll
  for (int w = 0; w < 4; ++w) { int v = wtot[w]; tot += v; if (w < wave) woff += v; }
  int c0 = min(tot, CAPE);
  int p = woff + incl - cnt;          // exclusive prefix for this thread's first token
#pragma unroll
  for (int i = 0; i < 16; ++i) {
    if ((pk[i] & 15) == e) { ws->pos0[base + t * 16 + i] = (p < CAPE) ? p : -1; ++p; }
  }
  __syncthreads();   // wtot reuse

  // ---- k = 1 (offset by capacity-clipped top-1 count) ----
  cnt = 0;
#pragma unroll
  for (int i = 0; i < 16; ++i) cnt += ((((pk[i] >> 4) & 15) == e) && (pk[i] & 0x100));
  incl = cnt;
#pragma unroll
  for (int off = 1; off < 64; off <<= 1) { int v = __shfl_up(incl, off, 64); if (lane >= off) incl += v; }
  if (lane == 63) wtot[wave] = incl;
  __syncthreads();
  woff = 0;
#pragma unroll
  for (int w = 0; w < 4; ++w) { int v = wtot[w]; if (w < wave) woff += v; }
  p = woff + incl - cnt;
#pragma unroll
  for (int i = 0; i < 16; ++i) {
    if ((((pk[i] >> 4) & 15) == e)) {
      if (pk[i] & 0x100) { int q = p + c0; ws->pos1[base + t * 16 + i] = (q < CAPE) ? q : -1; ++p; }
      else               { ws->pos1[base + t * 16 + i] = -1; }
    }
  }

  if (t == 0) {
    ws->proxy[be] = wsum[0] + wsum[1] + wsum[2] + wsum[3];
    ws->zpart[be] = zsum[0] + zsum[1] + zsum[2] + zsum[3];
    ws->cnt0[be]  = c0;
  }
}

// ---------------- fused zero-fill + scatter + loss epilogue ----------------
// one 256-thread block per token: writes that token's 5120-float row of
// dispatch AND combine in a single streaming pass, nonzeros inserted inline.
__global__ __launch_bounds__(256) void kout(const Ws* __restrict__ ws, float* __restrict__ out) {
  int token = blockIdx.x;
  int t = threadIdx.x;
  int pkv = ws->pk[token];
  int e0 = pkv & 15, e1 = (pkv >> 4) & 15;
  int p0 = ws->pos0[token], p1 = ws->pos1[token];
  float g0 = ws->g0[token], g1 = ws->g1[token];
  int o0 = (p0 >= 0) ? e0 * CAPE + p0 : -16;    // -16: never matches any rel in [0,4)
  int o1 = (p1 >= 0) ? e1 * CAPE + p1 : -16;

  float* drow = out + (size_t)token * ROW;
  float* crow = out + DCNT + (size_t)token * ROW;

#pragma unroll
  for (int c = 0; c < 5; ++c) {
    int off = c * 1024 + t * 4;
    int r0 = o0 - off, r1 = o1 - off;
    float4 dv, cv;
    dv.x = ((r0 == 0) | (r1 == 0)) ? 1.f : 0.f;
    dv.y = ((r0 == 1) | (r1 == 1)) ? 1.f : 0.f;
    dv.z = ((r0 == 2) | (r1 == 2)) ? 1.f : 0.f;
    dv.w = ((r0 == 3) | (r1 == 3)) ? 1.f : 0.f;
    cv.x = (r0 == 0) ? g0 : ((r1 == 0) ? g1 : 0.f);
    cv.y = (r0 == 1) ? g0 : ((r1 == 1) ? g1 : 0.f);
    cv.z = (r0 == 2) ? g0 : ((r1 == 2) ? g1 : 0.f);
    cv.w = (r0 == 3) ? g0 : ((r1 == 3) ? g1 : 0.f);
    *(float4*)(drow + off) = dv;
    *(float4*)(crow + off) = cv;
  }

  if (token == 0 && t == 0) {
    float bal = 0.f, z = 0.f;
#pragma unroll
    for (int i = 0; i < 16; ++i) {
      bal += (ws->proxy[i] * (1.f / NSEQ)) * ((float)ws->cnt0[i] * (1.f / NSEQ));
      z   += ws->zpart[i];
    }
    out[2 * DCNT]     = bal * 4.f;           // /16 * NUM_GATES^2
    out[2 * DCNT + 1] = z * (1.f / NTOK);
  }
}

extern "C" void kernel_launch(void* const* d_in, const int* in_sizes, int n_in,
                              void* d_out, int out_size, void* d_ws, size_t ws_size,
                              hipStream_t stream) {
  const float* x     = (const float*)d_in[0];
  const float* W     = (const float*)d_in[1];
  const float* probs = (const float*)d_in[2];
  float* out = (float*)d_out;
  Ws* ws = (Ws*)d_ws;

  kgate<<<NTOK / 32, 512, 0, stream>>>(x, W, probs, ws);
  kscan<<<16, 256, 0, stream>>>(ws);
  kout<<<NTOK, 256, 0, stream>>>(ws, out);
}

// Round 7
// 116.513 us; speedup vs baseline: 1.8390x; 1.7065x over previous
//
#include <hip/hip_runtime.h>

// TopNGating: B=2, N=4096, DIM=2048, 8 experts, top-2, cap=640
// Outputs (concat): dispatch[2,4096,8,640], combine[2,4096,8,640], balance_loss, router_z_loss

#define DIMX 2048
#define NG   8
#define NB   2
#define NSEQ 4096
#define NTOK (NB*NSEQ)
#define CAPE 640
#define ROW  (NG*CAPE)                 // 5120 floats per token per tensor
#define DCNT ((size_t)NTOK*ROW)        // 41943040 floats per dense output

struct Ws {
  int   pk[NTOK];                 // e0 | e1<<4 | routed1<<8
  float g0[NTOK];                 // renormalized top-1 gate
  float g1[NTOK];                 // renormalized top-2 gate
  float z2[NTOK];                 // lse^2 per token
  int   pos0[NTOK];               // capacity slot or -1
  int   pos1[NTOK];
  float raws_t[NG][NTOK];         // raw softmax gates, transposed [e][token]
  float proxy[16];                // per (b,e) sum of raw gates over n
  float zpart[16];                // per-block partial of sum(z2)
  int   cnt0[16];                 // per (b,e) capacity-clipped top-1 count
};

// ---------------- gate logits + softmax + top2 + routing decisions ----------------
// 512 blocks x 512 threads (8 waves); each wave gates 2 tokens (W LDS reads
// halved vs 1-tok). NO min-waves launch bound: R5/R6's (512,4) forced a
// 128-VGPR cap -> scratch spills -> 4x kgate regression. acc[2][8]=16 regs
// fits comfortably; LDS (64KB) caps occupancy at 2 blocks/CU anyway.
__global__ __launch_bounds__(512) void kgate(const float* __restrict__ x,
                                             const float* __restrict__ W,
                                             const float* __restrict__ probs,
                                             Ws* __restrict__ ws) {
  __shared__ float4 Wl[NG * 512];
  int tid = threadIdx.x;
  for (int i = tid; i < NG * 512; i += 512) Wl[i] = ((const float4*)W)[i];
  __syncthreads();

  int wave = tid >> 6, lane = tid & 63;
  int t0 = blockIdx.x * 16 + wave * 2;          // grid = NTOK/16 = 512 blocks

  const float4* xp0 = (const float4*)(x + (size_t)(t0 + 0) * DIMX);
  const float4* xp1 = (const float4*)(x + (size_t)(t0 + 1) * DIMX);

  float acc[2][NG];
#pragma unroll
  for (int tk = 0; tk < 2; ++tk)
#pragma unroll
    for (int e = 0; e < NG; ++e) acc[tk][e] = 0.f;

#pragma unroll
  for (int j = 0; j < 8; ++j) {
    float4 x0 = xp0[j * 64 + lane];
    float4 x1 = xp1[j * 64 + lane];
#pragma unroll
    for (int e = 0; e < NG; ++e) {
      float4 w = Wl[e * 512 + j * 64 + lane];
      acc[0][e] = fmaf(x0.x, w.x, acc[0][e]);
      acc[0][e] = fmaf(x0.y, w.y, acc[0][e]);
      acc[0][e] = fmaf(x0.z, w.z, acc[0][e]);
      acc[0][e] = fmaf(x0.w, w.w, acc[0][e]);
      acc[1][e] = fmaf(x1.x, w.x, acc[1][e]);
      acc[1][e] = fmaf(x1.y, w.y, acc[1][e]);
      acc[1][e] = fmaf(x1.z, w.z, acc[1][e]);
      acc[1][e] = fmaf(x1.w, w.w, acc[1][e]);
    }
  }

#pragma unroll
  for (int tk = 0; tk < 2; ++tk) {
    int token = t0 + tk;
    float a[NG];
#pragma unroll
    for (int e = 0; e < NG; ++e) a[e] = acc[tk][e];
#pragma unroll
    for (int e = 0; e < NG; ++e) {
#pragma unroll
      for (int off = 32; off > 0; off >>= 1) a[e] += __shfl_xor(a[e], off, 64);
    }

    // softmax over 8 gates (wave-uniform, redundant on all lanes)
    float m = a[0];
#pragma unroll
    for (int e = 1; e < NG; ++e) m = fmaxf(m, a[e]);
    float ex[NG], s = 0.f;
#pragma unroll
    for (int e = 0; e < NG; ++e) { ex[e] = expf(a[e] - m); s += ex[e]; }
    float raw[NG];
#pragma unroll
    for (int e = 0; e < NG; ++e) raw[e] = ex[e] / s;

    // top-2, ties -> lowest index (strict >)
    int e0i = 0; float g0v = raw[0];
#pragma unroll
    for (int e = 1; e < NG; ++e) if (raw[e] > g0v) { g0v = raw[e]; e0i = e; }
    int e1i = -1; float g1v = -1.f;
#pragma unroll
    for (int e = 0; e < NG; ++e) if (e != e0i && raw[e] > g1v) { g1v = raw[e]; e1i = e; }

    float denom = g0v + g1v;
    if (denom < 1e-9f) denom = 1e-9f;
    float g0n = g0v / denom, g1n = g1v / denom;

    float p1 = probs[NTOK + token];               // probs[1][b][n], b*NSEQ+n == token
    int r = (p1 < (g1n / 0.2f)) ? 1 : 0;          // threshold_train = 0.2

    float lse = m + logf(s);

    if (lane < NG) ws->raws_t[lane][token] = raw[lane];
    if (lane == 0) {
      ws->pk[token] = e0i | (e1i << 4) | (r << 8);
      ws->g0[token] = g0n;  ws->g1[token] = g1n;
      ws->z2[token] = lse * lse;
    }
  }
}

// ---------------- per-(b,e) exclusive prefix scans with capacity + loss partials ----------------
__global__ __launch_bounds__(256) void kscan(Ws* __restrict__ ws) {
  __shared__ int   wtot[4];
  __shared__ float wsum[4];
  __shared__ float zsum[4];
  int be = blockIdx.x, b = be >> 3, e = be & 7;
  int t = threadIdx.x, wave = t >> 6, lane = t & 63;
  int base = b * NSEQ;

  // each thread owns 16 consecutive tokens; wave covers contiguous 4KB -> coalesced int4
  int pk[16];
  {
    const int4* pp = (const int4*)(ws->pk + base + t * 16);
#pragma unroll
    for (int j = 0; j < 4; ++j) {
      int4 v = pp[j];
      pk[4*j] = v.x; pk[4*j+1] = v.y; pk[4*j+2] = v.z; pk[4*j+3] = v.w;
    }
  }

  // density_1_proxy partial: sum raw gates for this (b,e)  (transposed -> contiguous)
  float ps = 0.f;
  {
    const float* rp = ws->raws_t[e] + base + t * 16;
#pragma unroll
    for (int i = 0; i < 16; ++i) ps += rp[i];
  }
#pragma unroll
  for (int off = 32; off > 0; off >>= 1) ps += __shfl_xor(ps, off, 64);
  if (lane == 0) wsum[wave] = ps;

  // z-loss slice: this block reduces z2[be*512 .. be*512+512) = 128 float4s
  float zs = 0.f;
  if (t < 128) {
    float4 v = ((const float4*)ws->z2)[be * 128 + t];
    zs = v.x + v.y + v.z + v.w;
  }
#pragma unroll
  for (int off = 32; off > 0; off >>= 1) zs += __shfl_xor(zs, off, 64);
  if (lane == 0) zsum[wave] = zs;

  // ---- k = 0 (always routed) ----
  int cnt = 0;
#pragma unroll
  for (int i = 0; i < 16; ++i) cnt += ((pk[i] & 15) == e);
  int incl = cnt;
#pragma unroll
  for (int off = 1; off < 64; off <<= 1) { int v = __shfl_up(incl, off, 64); if (lane >= off) incl += v; }
  if (lane == 63) wtot[wave] = incl;
  __syncthreads();
  int woff = 0, tot = 0;
#pragma unroll
  for (int w = 0; w < 4; ++w) { int v = wtot[w]; tot += v; if (w < wave) woff += v; }
  int c0 = min(tot, CAPE);
  int p = woff + incl - cnt;          // exclusive prefix for this thread's first token
#pragma unroll
  for (int i = 0; i < 16; ++i) {
    if ((pk[i] & 15) == e) { ws->pos0[base + t * 16 + i] = (p < CAPE) ? p : -1; ++p; }
  }
  __syncthreads();   // wtot reuse

  // ---- k = 1 (offset by capacity-clipped top-1 count) ----
  cnt = 0;
#pragma unroll
  for (int i = 0; i < 16; ++i) cnt += ((((pk[i] >> 4) & 15) == e) && (pk[i] & 0x100));
  incl = cnt;
#pragma unroll
  for (int off = 1; off < 64; off <<= 1) { int v = __shfl_up(incl, off, 64); if (lane >= off) incl += v; }
  if (lane == 63) wtot[wave] = incl;
  __syncthreads();
  woff = 0;
#pragma unroll
  for (int w = 0; w < 4; ++w) { int v = wtot[w]; if (w < wave) woff += v; }
  p = woff + incl - cnt;
#pragma unroll
  for (int i = 0; i < 16; ++i) {
    if ((((pk[i] >> 4) & 15) == e)) {
      if (pk[i] & 0x100) { int q = p + c0; ws->pos1[base + t * 16 + i] = (q < CAPE) ? q : -1; ++p; }
      else               { ws->pos1[base + t * 16 + i] = -1; }
    }
  }

  if (t == 0) {
    ws->proxy[be] = wsum[0] + wsum[1] + wsum[2] + wsum[3];
    ws->zpart[be] = zsum[0] + zsum[1] + zsum[2] + zsum[3];
    ws->cnt0[be]  = c0;
  }
}

// ---------------- fused zero-fill + scatter + loss epilogue ----------------
// one 256-thread block per token: writes that token's 5120-float row of
// dispatch AND combine in a single streaming pass, nonzeros inserted inline.
__global__ __launch_bounds__(256) void kout(const Ws* __restrict__ ws, float* __restrict__ out) {
  int token = blockIdx.x;
  int t = threadIdx.x;
  int pkv = ws->pk[token];
  int e0 = pkv & 15, e1 = (pkv >> 4) & 15;
  int p0 = ws->pos0[token], p1 = ws->pos1[token];
  float g0 = ws->g0[token], g1 = ws->g1[token];
  int o0 = (p0 >= 0) ? e0 * CAPE + p0 : -16;    // -16: never matches any rel in [0,4)
  int o1 = (p1 >= 0) ? e1 * CAPE + p1 : -16;

  float* drow = out + (size_t)token * ROW;
  float* crow = out + DCNT + (size_t)token * ROW;

#pragma unroll
  for (int c = 0; c < 5; ++c) {
    int off = c * 1024 + t * 4;
    int r0 = o0 - off, r1 = o1 - off;
    float4 dv, cv;
    dv.x = ((r0 == 0) | (r1 == 0)) ? 1.f : 0.f;
    dv.y = ((r0 == 1) | (r1 == 1)) ? 1.f : 0.f;
    dv.z = ((r0 == 2) | (r1 == 2)) ? 1.f : 0.f;
    dv.w = ((r0 == 3) | (r1 == 3)) ? 1.f : 0.f;
    cv.x = (r0 == 0) ? g0 : ((r1 == 0) ? g1 : 0.f);
    cv.y = (r0 == 1) ? g0 : ((r1 == 1) ? g1 : 0.f);
    cv.z = (r0 == 2) ? g0 : ((r1 == 2) ? g1 : 0.f);
    cv.w = (r0 == 3) ? g0 : ((r1 == 3) ? g1 : 0.f);
    *(float4*)(drow + off) = dv;
    *(float4*)(crow + off) = cv;
  }

  if (token == 0 && t == 0) {
    float bal = 0.f, z = 0.f;
#pragma unroll
    for (int i = 0; i < 16; ++i) {
      bal += (ws->proxy[i] * (1.f / NSEQ)) * ((float)ws->cnt0[i] * (1.f / NSEQ));
      z   += ws->zpart[i];
    }
    out[2 * DCNT]     = bal * 4.f;           // /16 * NUM_GATES^2
    out[2 * DCNT + 1] = z * (1.f / NTOK);
  }
}

extern "C" void kernel_launch(void* const* d_in, const int* in_sizes, int n_in,
                              void* d_out, int out_size, void* d_ws, size_t ws_size,
                              hipStream_t stream) {
  const float* x     = (const float*)d_in[0];
  const float* W     = (const float*)d_in[1];
  const float* probs = (const float*)d_in[2];
  float* out = (float*)d_out;
  Ws* ws = (Ws*)d_ws;

  kgate<<<NTOK / 16, 512, 0, stream>>>(x, W, probs, ws);
  kscan<<<16, 256, 0, stream>>>(ws);
  kout<<<NTOK, 256, 0, stream>>>(ws, out);
}

// Round 9
// 91.220 us; speedup vs baseline: 2.3489x; 1.2773x over previous
//
#include <hip/hip_runtime.h>

// TopNGating: B=2, N=4096, DIM=2048, 8 experts, top-2, cap=640
// Outputs (concat): dispatch[2,4096,8,640], combine[2,4096,8,640], balance_loss, router_z_loss

#define DIMX 2048
#define NG   8
#define NB   2
#define NSEQ 4096
#define NTOK (NB*NSEQ)
#define CAPE 640
#define ROW  (NG*CAPE)                 // 5120 floats per token per tensor
#define DCNT ((size_t)NTOK*ROW)        // 41943040 floats per dense output

typedef float vfloat4 __attribute__((ext_vector_type(4)));   // native vec for nontemporal builtin

struct Ws {
  int   pk[NTOK];                 // e0 | e1<<4 | routed1<<8
  float g0[NTOK];                 // renormalized top-1 gate
  float g1[NTOK];                 // renormalized top-2 gate
  float z2[NTOK];                 // lse^2 per token
  int   pos0[NTOK];               // capacity slot or -1
  int   pos1[NTOK];
  float raws[(size_t)NTOK*NG];    // raw softmax gates [token][e]
  float proxy[16];                // per (b,e) sum of raw gates over n
  float zpart[16];                // per-block partial of sum(z2)
  int   cnt0[16];                 // per (b,e) capacity-clipped top-1 count
};

// ---------------- gate logits + softmax + top2 + routing decisions ----------------
// R2-exact 1-token-per-wave kernel (proven 93us config): ~90 VGPR, no spill,
// 2 blocks/CU (LDS-capped), W[8][2048] staged as float4 (64KB).
// 2-tok and 4-tok variants both regressed (VGPR cliff at 128 -> occupancy halved).
__global__ __launch_bounds__(512) void kgate(const float* __restrict__ x,
                                             const float* __restrict__ W,
                                             const float* __restrict__ probs,
                                             Ws* __restrict__ ws) {
  __shared__ float4 Wl[NG * 512];
  int tid = threadIdx.x;
  for (int i = tid; i < NG * 512; i += 512) Wl[i] = ((const float4*)W)[i];
  __syncthreads();

  int wave = tid >> 6, lane = tid & 63;
  int token = blockIdx.x * 8 + wave;            // grid = NTOK/8 blocks

  const float4* xp = (const float4*)(x + (size_t)token * DIMX);
  float4 xv[8];
#pragma unroll
  for (int j = 0; j < 8; ++j) xv[j] = xp[j * 64 + lane];   // coalesced 1KB/instr

  float acc[NG] = {0.f,0.f,0.f,0.f,0.f,0.f,0.f,0.f};
#pragma unroll
  for (int j = 0; j < 8; ++j) {
    float4 xj = xv[j];
#pragma unroll
    for (int e = 0; e < NG; ++e) {
      float4 w = Wl[e * 512 + j * 64 + lane];
      acc[e] = fmaf(xj.x, w.x, acc[e]);
      acc[e] = fmaf(xj.y, w.y, acc[e]);
      acc[e] = fmaf(xj.z, w.z, acc[e]);
      acc[e] = fmaf(xj.w, w.w, acc[e]);
    }
  }
#pragma unroll
  for (int e = 0; e < NG; ++e) {
#pragma unroll
    for (int off = 32; off > 0; off >>= 1) acc[e] += __shfl_xor(acc[e], off, 64);
  }

  // softmax over 8 gates (wave-uniform, redundant on all lanes)
  float m = acc[0];
#pragma unroll
  for (int e = 1; e < NG; ++e) m = fmaxf(m, acc[e]);
  float ex[NG], s = 0.f;
#pragma unroll
  for (int e = 0; e < NG; ++e) { ex[e] = expf(acc[e] - m); s += ex[e]; }
  float raw[NG];
#pragma unroll
  for (int e = 0; e < NG; ++e) raw[e] = ex[e] / s;

  // top-2, ties -> lowest index (strict >)
  int e0i = 0; float g0v = raw[0];
#pragma unroll
  for (int e = 1; e < NG; ++e) if (raw[e] > g0v) { g0v = raw[e]; e0i = e; }
  int e1i = -1; float g1v = -1.f;
#pragma unroll
  for (int e = 0; e < NG; ++e) if (e != e0i && raw[e] > g1v) { g1v = raw[e]; e1i = e; }

  float denom = g0v + g1v;
  if (denom < 1e-9f) denom = 1e-9f;
  float g0n = g0v / denom, g1n = g1v / denom;

  float p1 = probs[NTOK + token];               // probs[1][b][n], b*NSEQ+n == token
  int r = (p1 < (g1n / 0.2f)) ? 1 : 0;          // threshold_train = 0.2

  float lse = m + logf(s);

  if (lane < NG) ws->raws[(size_t)token * NG + lane] = raw[lane];
  if (lane == 0) {
    ws->pk[token] = e0i | (e1i << 4) | (r << 8);
    ws->g0[token] = g0n;  ws->g1[token] = g1n;
    ws->z2[token] = lse * lse;
  }
}

// ---------------- per-(b,e) exclusive prefix scans with capacity + loss partials ----------------
__global__ __launch_bounds__(256) void kscan(Ws* __restrict__ ws) {
  __shared__ int   wtot[4];
  __shared__ float wsum[4];
  __shared__ float zsum[4];
  int be = blockIdx.x, b = be >> 3, e = be & 7;
  int t = threadIdx.x, wave = t >> 6, lane = t & 63;
  int base = b * NSEQ;

  // each thread owns 16 consecutive tokens; wave covers contiguous 4KB -> coalesced int4
  int pk[16];
  {
    const int4* pp = (const int4*)(ws->pk + base + t * 16);
#pragma unroll
    for (int j = 0; j < 4; ++j) {
      int4 v = pp[j];
      pk[4*j] = v.x; pk[4*j+1] = v.y; pk[4*j+2] = v.z; pk[4*j+3] = v.w;
    }
  }

  // density_1_proxy partial: sum raw gates for this (b,e)
  float ps = 0.f;
#pragma unroll
  for (int i = 0; i < 16; ++i) ps += ws->raws[(size_t)(base + t * 16 + i) * NG + e];
#pragma unroll
  for (int off = 32; off > 0; off >>= 1) ps += __shfl_xor(ps, off, 64);
  if (lane == 0) wsum[wave] = ps;

  // z-loss slice: this block reduces z2[be*512 .. be*512+512) = 128 float4s
  float zs = 0.f;
  if (t < 128) {
    float4 v = ((const float4*)ws->z2)[be * 128 + t];
    zs = v.x + v.y + v.z + v.w;
  }
#pragma unroll
  for (int off = 32; off > 0; off >>= 1) zs += __shfl_xor(zs, off, 64);
  if (lane == 0) zsum[wave] = zs;

  // ---- k = 0 (always routed) ----
  int cnt = 0;
#pragma unroll
  for (int i = 0; i < 16; ++i) cnt += ((pk[i] & 15) == e);
  int incl = cnt;
#pragma unroll
  for (int off = 1; off < 64; off <<= 1) { int v = __shfl_up(incl, off, 64); if (lane >= off) incl += v; }
  if (lane == 63) wtot[wave] = incl;
  __syncthreads();
  int woff = 0, tot = 0;
#pragma unroll
  for (int w = 0; w < 4; ++w) { int v = wtot[w]; tot += v; if (w < wave) woff += v; }
  int c0 = min(tot, CAPE);
  int p = woff + incl - cnt;          // exclusive prefix for this thread's first token
#pragma unroll
  for (int i = 0; i < 16; ++i) {
    if ((pk[i] & 15) == e) { ws->pos0[base + t * 16 + i] = (p < CAPE) ? p : -1; ++p; }
  }
  __syncthreads();   // wtot reuse

  // ---- k = 1 (offset by capacity-clipped top-1 count) ----
  cnt = 0;
#pragma unroll
  for (int i = 0; i < 16; ++i) cnt += ((((pk[i] >> 4) & 15) == e) && (pk[i] & 0x100));
  incl = cnt;
#pragma unroll
  for (int off = 1; off < 64; off <<= 1) { int v = __shfl_up(incl, off, 64); if (lane >= off) incl += v; }
  if (lane == 63) wtot[wave] = incl;
  __syncthreads();
  woff = 0;
#pragma unroll
  for (int w = 0; w < 4; ++w) { int v = wtot[w]; if (w < wave) woff += v; }
  p = woff + incl - cnt;
#pragma unroll
  for (int i = 0; i < 16; ++i) {
    if ((((pk[i] >> 4) & 15) == e)) {
      if (pk[i] & 0x100) { int q = p + c0; ws->pos1[base + t * 16 + i] = (q < CAPE) ? q : -1; ++p; }
      else               { ws->pos1[base + t * 16 + i] = -1; }
    }
  }

  if (t == 0) {
    ws->proxy[be] = wsum[0] + wsum[1] + wsum[2] + wsum[3];
    ws->zpart[be] = zsum[0] + zsum[1] + zsum[2] + zsum[3];
    ws->cnt0[be]  = c0;
  }
}

// ---------------- fused zero-fill + scatter + loss epilogue ----------------
// 2 tokens per 256-thread block (grid NTOK/2): streams both tokens' 5120-float
// rows of dispatch AND combine with nontemporal float4 stores (output is never
// re-read by the kernel -> skip cache allocate).
__global__ __launch_bounds__(256) void kout(const Ws* __restrict__ ws, float* __restrict__ out) {
  int t = threadIdx.x;

#pragma unroll
  for (int tk = 0; tk < 2; ++tk) {
    int token = blockIdx.x * 2 + tk;
    int pkv = ws->pk[token];
    int e0 = pkv & 15, e1 = (pkv >> 4) & 15;
    int p0 = ws->pos0[token], p1 = ws->pos1[token];
    float g0 = ws->g0[token], g1 = ws->g1[token];
    int o0 = (p0 >= 0) ? e0 * CAPE + p0 : -16;    // -16: never matches any rel in [0,4)
    int o1 = (p1 >= 0) ? e1 * CAPE + p1 : -16;

    float* drow = out + (size_t)token * ROW;
    float* crow = out + DCNT + (size_t)token * ROW;

#pragma unroll
    for (int c = 0; c < 5; ++c) {
      int off = c * 1024 + t * 4;
      int r0 = o0 - off, r1 = o1 - off;
      vfloat4 dv, cv;
      dv.x = ((r0 == 0) | (r1 == 0)) ? 1.f : 0.f;
      dv.y = ((r0 == 1) | (r1 == 1)) ? 1.f : 0.f;
      dv.z = ((r0 == 2) | (r1 == 2)) ? 1.f : 0.f;
      dv.w = ((r0 == 3) | (r1 == 3)) ? 1.f : 0.f;
      cv.x = (r0 == 0) ? g0 : ((r1 == 0) ? g1 : 0.f);
      cv.y = (r0 == 1) ? g0 : ((r1 == 1) ? g1 : 0.f);
      cv.z = (r0 == 2) ? g0 : ((r1 == 2) ? g1 : 0.f);
      cv.w = (r0 == 3) ? g0 : ((r1 == 3) ? g1 : 0.f);
      __builtin_nontemporal_store(dv, (vfloat4*)(drow + off));
      __builtin_nontemporal_store(cv, (vfloat4*)(crow + off));
    }
  }

  if (blockIdx.x == 0 && t == 0) {
    float bal = 0.f, z = 0.f;
#pragma unroll
    for (int i = 0; i < 16; ++i) {
      bal += (ws->proxy[i] * (1.f / NSEQ)) * ((float)ws->cnt0[i] * (1.f / NSEQ));
      z   += ws->zpart[i];
    }
    out[2 * DCNT]     = bal * 4.f;           // /16 * NUM_GATES^2
    out[2 * DCNT + 1] = z * (1.f / NTOK);
  }
}

extern "C" void kernel_launch(void* const* d_in, const int* in_sizes, int n_in,
                              void* d_out, int out_size, void* d_ws, size_t ws_size,
                              hipStream_t stream) {
  const float* x     = (const float*)d_in[0];
  const float* W     = (const float*)d_in[1];
  const float* probs = (const float*)d_in[2];
  float* out = (float*)d_out;
  Ws* ws = (Ws*)d_ws;

  kgate<<<NTOK / 8, 512, 0, stream>>>(x, W, probs, ws);
  kscan<<<16, 256, 0, stream>>>(ws);
  kout<<<NTOK / 2, 256, 0, stream>>>(ws, out);
}

// Round 10
// 85.206 us; speedup vs baseline: 2.5147x; 1.0706x over previous
//
#include <hip/hip_runtime.h>

// TopNGating: B=2, N=4096, DIM=2048, 8 experts, top-2, cap=640
// Outputs (concat): dispatch[2,4096,8,640], combine[2,4096,8,640], balance_loss, router_z_loss
//
// Structure (R10): 2 kernels.
//  kfat: 5120 blocks, role-split by bid%5 -> 4096 zero-blocks (nt-store the
//        335.5MB of output zeros; HBM-write-bound) interleaved 4:1 with 1024
//        gate-blocks (R9-exact gate math; DS-pipe/HBM-read-bound). Different
//        pipes -> co-resident waves overlap (time ~ max, not sum).
//  kscan: 16 (b,e) blocks: prefix scan + DIRECT scatter of the <=2 nonzeros
//        per token into the zeroed rows (R2-proven) + loss atomicAdds.

#define DIMX 2048
#define NG   8
#define NB   2
#define NSEQ 4096
#define NTOK (NB*NSEQ)
#define CAPE 640
#define ROW  (NG*CAPE)                 // 5120 floats per token per tensor
#define DCNT ((size_t)NTOK*ROW)        // 41943040 floats per dense output

typedef float vfloat4 __attribute__((ext_vector_type(4)));   // native vec for nontemporal builtin

struct Ws {
  int   pk[NTOK];                 // e0 | e1<<4 | routed1<<8
  float g0[NTOK];                 // renormalized top-1 gate
  float g1[NTOK];                 // renormalized top-2 gate
  float z2[NTOK];                 // lse^2 per token
  float raws[(size_t)NTOK*NG];    // raw softmax gates [token][e]
};

// ---------------- fused: zero-fill (4/5 of blocks) + gate (1/5 of blocks) ----------------
__global__ __launch_bounds__(512) void kfat(const float* __restrict__ x,
                                            const float* __restrict__ W,
                                            const float* __restrict__ probs,
                                            Ws* __restrict__ ws,
                                            float* __restrict__ out) {
  __shared__ float4 Wl[NG * 512];
  int bid = blockIdx.x;
  int g = bid / 5, r = bid - g * 5;
  int tid = threadIdx.x;

  if (r != 4) {
    // ---- zero block: nt-stream 5120 float4s (80KB) of the dense outputs ----
    int idx = g * 4 + r;                        // 0..4095
    vfloat4* o4 = (vfloat4*)out;
    long base = (long)idx * 5120 + tid;
    vfloat4 z = {0.f, 0.f, 0.f, 0.f};
#pragma unroll
    for (int k = 0; k < 10; ++k) __builtin_nontemporal_store(z, o4 + base + k * 512);
    if (idx == 0 && tid == 0) { out[2 * DCNT] = 0.f; out[2 * DCNT + 1] = 0.f; }  // loss accum init
    return;
  }

  // ---- gate block g in [0,1024): R9-exact math, 1 token per wave ----
  for (int i = tid; i < NG * 512; i += 512) Wl[i] = ((const float4*)W)[i];
  __syncthreads();

  int wave = tid >> 6, lane = tid & 63;
  int token = g * 8 + wave;

  const float4* xp = (const float4*)(x + (size_t)token * DIMX);
  float4 xv[8];
#pragma unroll
  for (int j = 0; j < 8; ++j) xv[j] = xp[j * 64 + lane];   // coalesced 1KB/instr

  float acc[NG] = {0.f,0.f,0.f,0.f,0.f,0.f,0.f,0.f};
#pragma unroll
  for (int j = 0; j < 8; ++j) {
    float4 xj = xv[j];
#pragma unroll
    for (int e = 0; e < NG; ++e) {
      float4 w = Wl[e * 512 + j * 64 + lane];
      acc[e] = fmaf(xj.x, w.x, acc[e]);
      acc[e] = fmaf(xj.y, w.y, acc[e]);
      acc[e] = fmaf(xj.z, w.z, acc[e]);
      acc[e] = fmaf(xj.w, w.w, acc[e]);
    }
  }
#pragma unroll
  for (int e = 0; e < NG; ++e) {
#pragma unroll
    for (int off = 32; off > 0; off >>= 1) acc[e] += __shfl_xor(acc[e], off, 64);
  }

  // softmax over 8 gates (wave-uniform, redundant on all lanes)
  float m = acc[0];
#pragma unroll
  for (int e = 1; e < NG; ++e) m = fmaxf(m, acc[e]);
  float ex[NG], s = 0.f;
#pragma unroll
  for (int e = 0; e < NG; ++e) { ex[e] = expf(acc[e] - m); s += ex[e]; }
  float raw[NG];
#pragma unroll
  for (int e = 0; e < NG; ++e) raw[e] = ex[e] / s;

  // top-2, ties -> lowest index (strict >)
  int e0i = 0; float g0v = raw[0];
#pragma unroll
  for (int e = 1; e < NG; ++e) if (raw[e] > g0v) { g0v = raw[e]; e0i = e; }
  int e1i = -1; float g1v = -1.f;
#pragma unroll
  for (int e = 0; e < NG; ++e) if (e != e0i && raw[e] > g1v) { g1v = raw[e]; e1i = e; }

  float denom = g0v + g1v;
  if (denom < 1e-9f) denom = 1e-9f;
  float g0n = g0v / denom, g1n = g1v / denom;

  float p1 = probs[NTOK + token];               // probs[1][b][n], b*NSEQ+n == token
  int rte = (p1 < (g1n / 0.2f)) ? 1 : 0;        // threshold_train = 0.2

  float lse = m + logf(s);

  if (lane < NG) ws->raws[(size_t)token * NG + lane] = raw[lane];
  if (lane == 0) {
    ws->pk[token] = e0i | (e1i << 4) | (rte << 8);
    ws->g0[token] = g0n;  ws->g1[token] = g1n;
    ws->z2[token] = lse * lse;
  }
}

// ---------------- per-(b,e) prefix scans + direct scatter + loss accumulation ----------------
__global__ __launch_bounds__(256) void kscan(const Ws* __restrict__ ws, float* __restrict__ out) {
  __shared__ int   wtot[4];
  __shared__ float wsum[4];
  __shared__ float zsum[4];
  int be = blockIdx.x, b = be >> 3, e = be & 7;
  int t = threadIdx.x, wave = t >> 6, lane = t & 63;
  int base = b * NSEQ;

  // each thread owns 16 consecutive tokens; wave covers contiguous 4KB -> coalesced int4
  int pk[16];
  {
    const int4* pp = (const int4*)(ws->pk + base + t * 16);
#pragma unroll
    for (int j = 0; j < 4; ++j) {
      int4 v = pp[j];
      pk[4*j] = v.x; pk[4*j+1] = v.y; pk[4*j+2] = v.z; pk[4*j+3] = v.w;
    }
  }

  // density_1_proxy partial: sum raw gates for this (b,e)
  float ps = 0.f;
#pragma unroll
  for (int i = 0; i < 16; ++i) ps += ws->raws[(size_t)(base + t * 16 + i) * NG + e];
#pragma unroll
  for (int off = 32; off > 0; off >>= 1) ps += __shfl_xor(ps, off, 64);
  if (lane == 0) wsum[wave] = ps;

  // z-loss slice: this block reduces z2[be*512 .. be*512+512) = 128 float4s
  float zs = 0.f;
  if (t < 128) {
    float4 v = ((const float4*)ws->z2)[be * 128 + t];
    zs = v.x + v.y + v.z + v.w;
  }
#pragma unroll
  for (int off = 32; off > 0; off >>= 1) zs += __shfl_xor(zs, off, 64);
  if (lane == 0) zsum[wave] = zs;

  // ---- k = 0 (always routed) ----
  int cnt = 0;
#pragma unroll
  for (int i = 0; i < 16; ++i) cnt += ((pk[i] & 15) == e);
  int incl = cnt;
#pragma unroll
  for (int off = 1; off < 64; off <<= 1) { int v = __shfl_up(incl, off, 64); if (lane >= off) incl += v; }
  if (lane == 63) wtot[wave] = incl;
  __syncthreads();
  int woff = 0, tot = 0;
#pragma unroll
  for (int w = 0; w < 4; ++w) { int v = wtot[w]; tot += v; if (w < wave) woff += v; }
  int c0 = min(tot, CAPE);
  int p = woff + incl - cnt;          // exclusive prefix for this thread's first token
#pragma unroll
  for (int i = 0; i < 16; ++i) {
    int nn = t * 16 + i;
    if ((pk[i] & 15) == e) {
      if (p < CAPE) {
        size_t o = (size_t)(base + nn) * ROW + e * CAPE + p;
        out[o]        = 1.f;                       // dispatch
        out[DCNT + o] = ws->g0[base + nn];         // combine
      }
      ++p;
    }
  }
  __syncthreads();   // wtot reuse

  // ---- k = 1 (offset by capacity-clipped top-1 count) ----
  cnt = 0;
#pragma unroll
  for (int i = 0; i < 16; ++i) cnt += ((((pk[i] >> 4) & 15) == e) && (pk[i] & 0x100));
  incl = cnt;
#pragma unroll
  for (int off = 1; off < 64; off <<= 1) { int v = __shfl_up(incl, off, 64); if (lane >= off) incl += v; }
  if (lane == 63) wtot[wave] = incl;
  __syncthreads();
  woff = 0;
#pragma unroll
  for (int w = 0; w < 4; ++w) { int v = wtot[w]; if (w < wave) woff += v; }
  p = woff + incl - cnt;
#pragma unroll
  for (int i = 0; i < 16; ++i) {
    int nn = t * 16 + i;
    if ((((pk[i] >> 4) & 15) == e) && (pk[i] & 0x100)) {
      int q = p + c0;
      if (q < CAPE) {
        size_t o = (size_t)(base + nn) * ROW + e * CAPE + q;
        out[o]        = 1.f;                       // dispatch
        out[DCNT + o] = ws->g1[base + nn];         // combine
      }
      ++p;
    }
  }

  if (t == 0) {
    float psum = wsum[0] + wsum[1] + wsum[2] + wsum[3];
    float ztot = zsum[0] + zsum[1] + zsum[2] + zsum[3];
    // balance: sum over 16 (b,e) of (proxy/NSEQ)*(c0/NSEQ), /16 * 64
    atomicAdd(out + 2 * DCNT,     psum * (1.f / NSEQ) * ((float)c0 * (1.f / NSEQ)) * 4.f);
    atomicAdd(out + 2 * DCNT + 1, ztot * (1.f / NTOK));
  }
}

extern "C" void kernel_launch(void* const* d_in, const int* in_sizes, int n_in,
                              void* d_out, int out_size, void* d_ws, size_t ws_size,
                              hipStream_t stream) {
  const float* x     = (const float*)d_in[0];
  const float* W     = (const float*)d_in[1];
  const float* probs = (const float*)d_in[2];
  float* out = (float*)d_out;
  Ws* ws = (Ws*)d_ws;

  kfat<<<5120, 512, 0, stream>>>(x, W, probs, ws, out);
  kscan<<<16, 256, 0, stream>>>(ws, out);
}